// Round 2
// baseline (12312.437 us; speedup 1.0000x reference)
//
#include <hip/hip_runtime.h>
#include <hip/hip_bf16.h>

#define N_USERS   100000
#define N_ITEMS   50000
#define N_NODES_C 150000
#define EMB       64
#define N_ELEM    (N_NODES_C * EMB)   // 9,600,000

// ---- runtime dtype detection (fp32 vs bf16-packed) ----
// flags[0] = emb (and output) is bf16 ? 1 : 0
// flags[1] = adj_vals is bf16 ? 1 : 0
__global__ void detect_dtypes(const unsigned int* __restrict__ emb_u32,
                              const unsigned int* __restrict__ vals_u32,
                              int* __restrict__ flags) {
    int t = threadIdx.x;
    int cnt_emb = 0, cnt_vals = 0;
    for (int k = t; k < 1024; k += 256) {
        // emb: low-half exponent field. bf16-packed -> in [100,127] ~99%;
        // fp32 mantissa bits -> uniform byte (~11% in range).
        unsigned e = (emb_u32[k] >> 7) & 0xFFu;
        cnt_emb += (e >= 100u && e <= 127u) ? 1 : 0;
        // vals: low-half bit15. bf16-packed -> sign of a nonneg value = 0;
        // fp32 -> random mantissa bit (p=0.5).
        cnt_vals += (vals_u32[k] >> 15) & 1u;
    }
    __shared__ int s0[256], s1[256];
    s0[t] = cnt_emb; s1[t] = cnt_vals;
    __syncthreads();
    for (int s = 128; s > 0; s >>= 1) {
        if (t < s) { s0[t] += s0[t + s]; s1[t] += s1[t + s]; }
        __syncthreads();
    }
    if (t == 0) {
        flags[0] = (s0[0] > 512) ? 1 : 0;
        flags[1] = (s1[0] > 100) ? 0 : 1;
    }
}

__device__ __forceinline__ float load_f(const void* base, int i, int is_bf16) {
    if (is_bf16) return __bfloat162float(((const __hip_bfloat16*)base)[i]);
    return ((const float*)base)[i];
}
__device__ __forceinline__ void store_f(void* base, int i, int is_bf16, float v) {
    if (is_bf16) ((__hip_bfloat16*)base)[i] = __float2bfloat16(v);
    else ((float*)base)[i] = v;
}

// ---- init: h = ego (fp32); out = ego (native dtype, running sum) ----
__global__ void init_kernel(const void* __restrict__ eu,
                            const void* __restrict__ ei,
                            float* __restrict__ h,
                            void* __restrict__ out,
                            const int* __restrict__ flags) {
    int i = blockIdx.x * blockDim.x + threadIdx.x;
    if (i >= N_ELEM) return;
    int ebf = flags[0];
    float f = (i < N_USERS * EMB) ? load_f(eu, i, ebf)
                                  : load_f(ei, i - N_USERS * EMB, ebf);
    h[i] = f;
    store_f(out, i, ebf, f);
}

// ---- scatter SpMM: y[rows[e]] += vals[e] * x[cols[e]] ----
// 16 threads/edge, float4 per thread. x,y are fp32 ws buffers.
__global__ void spmm_scatter(const float* __restrict__ x,
                             float* __restrict__ y,
                             const void* __restrict__ vals,
                             const int* __restrict__ rows,
                             const int* __restrict__ cols,
                             int nnz,
                             const int* __restrict__ flags) {
    int tid  = blockIdx.x * blockDim.x + threadIdx.x;
    int edge = tid >> 4;
    if (edge >= nnz) return;
    int sub = (tid & 15) << 2;

    int   r = rows[edge];
    int   c = cols[edge];
    float v = load_f(vals, edge, flags[1]);

    const float4 xv = *reinterpret_cast<const float4*>(x + (size_t)c * EMB + sub);
    float* yp = y + (size_t)r * EMB + sub;
    atomicAdd(yp + 0, v * xv.x);
    atomicAdd(yp + 1, v * xv.y);
    atomicAdd(yp + 2, v * xv.z);
    atomicAdd(yp + 3, v * xv.w);
}

// ---- out += h (native dtype read-modify-write) ----
__global__ void acc_add_out(void* __restrict__ out, const float* __restrict__ h,
                            const int* __restrict__ flags) {
    int i = blockIdx.x * blockDim.x + threadIdx.x;
    if (i >= N_ELEM) return;
    int ebf = flags[0];
    store_f(out, i, ebf, load_f(out, i, ebf) + h[i]);
}

// ---- out *= 0.25 ----
__global__ void finalize(void* __restrict__ out, const int* __restrict__ flags) {
    int i = blockIdx.x * blockDim.x + threadIdx.x;
    if (i >= N_ELEM) return;
    int ebf = flags[0];
    store_f(out, i, ebf, load_f(out, i, ebf) * 0.25f);
}

extern "C" void kernel_launch(void* const* d_in, const int* in_sizes, int n_in,
                              void* d_out, int out_size, void* d_ws, size_t ws_size,
                              hipStream_t stream) {
    const void* eu   = d_in[0];
    const void* ei   = d_in[1];
    const void* vals = d_in[2];
    const int*  rows = (const int*)d_in[3];
    const int*  cols = (const int*)d_in[4];
    const int nnz = in_sizes[2];

    float* hA = (float*)d_ws;
    float* hB = hA + N_ELEM;
    int* flags = (int*)(hB + N_ELEM);

    detect_dtypes<<<1, 256, 0, stream>>>((const unsigned int*)eu,
                                         (const unsigned int*)vals, flags);

    init_kernel<<<(N_ELEM + 255) / 256, 256, 0, stream>>>(eu, ei, hA, d_out, flags);

    float* x = hA;
    float* y = hB;
    for (int layer = 0; layer < 3; ++layer) {
        hipMemsetAsync(y, 0, (size_t)N_ELEM * sizeof(float), stream);
        long threads = (long)nnz * 16;
        spmm_scatter<<<(int)((threads + 255) / 256), 256, 0, stream>>>(
            x, y, vals, rows, cols, nnz, flags);
        acc_add_out<<<(N_ELEM + 255) / 256, 256, 0, stream>>>(d_out, y, flags);
        float* t = x; x = y; y = t;
    }

    finalize<<<(N_ELEM + 255) / 256, 256, 0, stream>>>(d_out, flags);
}

// Round 3
// 1752.840 us; speedup vs baseline: 7.0243x; 7.0243x over previous
//
#include <hip/hip_runtime.h>
#include <hip/hip_bf16.h>

#define N_USERS   100000
#define N_ITEMS   50000
#define N_NODES_C 150000
#define EMB       64
#define N_ELEM    (N_NODES_C * EMB)   // 9,600,000
#define SCAN_T    1024

// ---- runtime dtype detection (fp32 vs bf16-packed) ----
__global__ void detect_dtypes(const unsigned int* __restrict__ emb_u32,
                              const unsigned int* __restrict__ vals_u32,
                              int* __restrict__ flags) {
    int t = threadIdx.x;
    int cnt_emb = 0, cnt_vals = 0;
    for (int k = t; k < 1024; k += 256) {
        unsigned e = (emb_u32[k] >> 7) & 0xFFu;
        cnt_emb += (e >= 100u && e <= 127u) ? 1 : 0;
        cnt_vals += (vals_u32[k] >> 15) & 1u;
    }
    __shared__ int s0[256], s1[256];
    s0[t] = cnt_emb; s1[t] = cnt_vals;
    __syncthreads();
    for (int s = 128; s > 0; s >>= 1) {
        if (t < s) { s0[t] += s0[t + s]; s1[t] += s1[t + s]; }
        __syncthreads();
    }
    if (t == 0) {
        flags[0] = (s0[0] > 512) ? 1 : 0;   // emb/out bf16?
        flags[1] = (s1[0] > 100) ? 0 : 1;   // vals bf16?
    }
}

__device__ __forceinline__ float load_f(const void* base, int i, int is_bf16) {
    if (is_bf16) return __bfloat162float(((const __hip_bfloat16*)base)[i]);
    return ((const float*)base)[i];
}
__device__ __forceinline__ void store_f(void* base, int i, int is_bf16, float v) {
    if (is_bf16) ((__hip_bfloat16*)base)[i] = __float2bfloat16(v);
    else ((float*)base)[i] = v;
}

// ---- init: h = ego (fp32); out = ego (native dtype, running sum) ----
__global__ void init_kernel(const void* __restrict__ eu,
                            const void* __restrict__ ei,
                            float* __restrict__ h,
                            void* __restrict__ out,
                            const int* __restrict__ flags) {
    int i = blockIdx.x * blockDim.x + threadIdx.x;
    if (i >= N_ELEM) return;
    int ebf = flags[0];
    float f = (i < N_USERS * EMB) ? load_f(eu, i, ebf)
                                  : load_f(ei, i - N_USERS * EMB, ebf);
    h[i] = f;
    store_f(out, i, ebf, f);
}

// ---- CSR build A: histogram of rows (counts in row_off) ----
__global__ void hist_rows(const int* __restrict__ rows, int* __restrict__ counts, int nnz) {
    int i = blockIdx.x * blockDim.x + threadIdx.x;
    if (i < nnz) atomicAdd(&counts[rows[i]], 1);
}

// ---- B: single-block exclusive scan; row_off(counts) -> row_ptr + row_off(prefix) ----
__global__ void scan_rows(int* __restrict__ row_off, int* __restrict__ row_ptr) {
    __shared__ int part[SCAN_T];
    int t = threadIdx.x;
    const int CH = (N_NODES_C + SCAN_T - 1) / SCAN_T;
    int beg = t * CH;
    int end = beg + CH; if (end > N_NODES_C) end = N_NODES_C;
    int s = 0;
    for (int i = beg; i < end; ++i) s += row_off[i];
    part[t] = s;
    __syncthreads();
    for (int off = 1; off < SCAN_T; off <<= 1) {
        int v = (t >= off) ? part[t - off] : 0;
        __syncthreads();
        part[t] += v;
        __syncthreads();
    }
    int run = part[t] - s;
    for (int i = beg; i < end; ++i) {
        int c = row_off[i];
        row_ptr[i] = run;
        row_off[i] = run;
        run += c;
    }
    if (t == SCAN_T - 1) row_ptr[N_NODES_C] = run;
}

// ---- C: scatter edges into CSR order ----
__global__ void scatter_edges(const int* __restrict__ rows, const int* __restrict__ cols,
                              const void* __restrict__ vals,
                              int* __restrict__ row_off,
                              int* __restrict__ scol, float* __restrict__ sval,
                              int nnz, const int* __restrict__ flags) {
    int i = blockIdx.x * blockDim.x + threadIdx.x;
    if (i >= nnz) return;
    int r = rows[i];
    int pos = atomicAdd(&row_off[r], 1);
    scol[pos] = cols[i];
    sval[pos] = load_f(vals, i, flags[1]);
}

// ---- CSR SpMM: one wave per row, lane = emb dim; fused out += y. No atomics. ----
__global__ void spmm_csr(const float* __restrict__ x, float* __restrict__ y,
                         void* __restrict__ out,
                         const float* __restrict__ sval, const int* __restrict__ scol,
                         const int* __restrict__ row_ptr,
                         const int* __restrict__ flags) {
    int row = blockIdx.x * (blockDim.x >> 6) + (threadIdx.x >> 6);
    if (row >= N_NODES_C) return;
    int lane = threadIdx.x & 63;
    int beg = row_ptr[row], end = row_ptr[row + 1];
    float acc = 0.f;
    int e = beg;
    for (; e + 1 < end; e += 2) {
        int   c0 = scol[e],     c1 = scol[e + 1];
        float v0 = sval[e],     v1 = sval[e + 1];
        float x0 = x[(size_t)c0 * EMB + lane];
        float x1 = x[(size_t)c1 * EMB + lane];
        acc += v0 * x0;
        acc += v1 * x1;
    }
    if (e < end) acc += sval[e] * x[(size_t)scol[e] * EMB + lane];
    size_t i = (size_t)row * EMB + lane;
    y[i] = acc;
    int ebf = flags[0];
    store_f(out, i, ebf, load_f(out, i, ebf) + acc);
}

// ---- out *= 0.25 ----
__global__ void finalize(void* __restrict__ out, const int* __restrict__ flags) {
    int i = blockIdx.x * blockDim.x + threadIdx.x;
    if (i >= N_ELEM) return;
    int ebf = flags[0];
    store_f(out, i, ebf, load_f(out, i, ebf) * 0.25f);
}

// ---- fallback (atomic) path, only if ws_size too small for CSR ----
__global__ void spmm_scatter(const float* __restrict__ x, float* __restrict__ y,
                             const void* __restrict__ vals,
                             const int* __restrict__ rows, const int* __restrict__ cols,
                             int nnz, const int* __restrict__ flags) {
    int tid  = blockIdx.x * blockDim.x + threadIdx.x;
    int edge = tid >> 4;
    if (edge >= nnz) return;
    int sub = (tid & 15) << 2;
    int r = rows[edge], c = cols[edge];
    float v = load_f(vals, edge, flags[1]);
    const float4 xv = *reinterpret_cast<const float4*>(x + (size_t)c * EMB + sub);
    float* yp = y + (size_t)r * EMB + sub;
    atomicAdd(yp + 0, v * xv.x);
    atomicAdd(yp + 1, v * xv.y);
    atomicAdd(yp + 2, v * xv.z);
    atomicAdd(yp + 3, v * xv.w);
}
__global__ void acc_add_out(void* __restrict__ out, const float* __restrict__ h,
                            const int* __restrict__ flags) {
    int i = blockIdx.x * blockDim.x + threadIdx.x;
    if (i >= N_ELEM) return;
    int ebf = flags[0];
    store_f(out, i, ebf, load_f(out, i, ebf) + h[i]);
}

extern "C" void kernel_launch(void* const* d_in, const int* in_sizes, int n_in,
                              void* d_out, int out_size, void* d_ws, size_t ws_size,
                              hipStream_t stream) {
    const void* eu   = d_in[0];
    const void* ei   = d_in[1];
    const void* vals = d_in[2];
    const int*  rows = (const int*)d_in[3];
    const int*  cols = (const int*)d_in[4];
    const int nnz = in_sizes[2];

    // ws layout
    float* hA      = (float*)d_ws;                   // N_ELEM
    float* hB      = hA + N_ELEM;                    // N_ELEM
    int*   row_ptr = (int*)(hB + N_ELEM);            // N_NODES_C+1
    int*   row_off = row_ptr + (N_NODES_C + 1);      // N_NODES_C
    int*   scol    = row_off + N_NODES_C;            // nnz
    float* sval    = (float*)(scol + nnz);           // nnz
    int*   flags   = (int*)(sval + nnz);             // 2
    size_t need_csr = (size_t)((char*)(flags + 2) - (char*)d_ws);

    bool use_csr = ws_size >= need_csr;
    if (!use_csr) {
        // minimal layout: hA, hB, flags
        flags = (int*)(hB + N_ELEM);
    }

    detect_dtypes<<<1, 256, 0, stream>>>((const unsigned int*)eu,
                                         (const unsigned int*)vals, flags);

    init_kernel<<<(N_ELEM + 255) / 256, 256, 0, stream>>>(eu, ei, hA, d_out, flags);

    if (use_csr) {
        hipMemsetAsync(row_off, 0, (size_t)N_NODES_C * sizeof(int), stream);
        hist_rows<<<(nnz + 255) / 256, 256, 0, stream>>>(rows, row_off, nnz);
        scan_rows<<<1, SCAN_T, 0, stream>>>(row_off, row_ptr);
        scatter_edges<<<(nnz + 255) / 256, 256, 0, stream>>>(rows, cols, vals, row_off,
                                                             scol, sval, nnz, flags);
        float* x = hA;
        float* y = hB;
        for (int layer = 0; layer < 3; ++layer) {
            spmm_csr<<<(N_NODES_C + 3) / 4, 256, 0, stream>>>(x, y, d_out, sval, scol,
                                                              row_ptr, flags);
            float* t = x; x = y; y = t;
        }
    } else {
        float* x = hA;
        float* y = hB;
        for (int layer = 0; layer < 3; ++layer) {
            hipMemsetAsync(y, 0, (size_t)N_ELEM * sizeof(float), stream);
            long threads = (long)nnz * 16;
            spmm_scatter<<<(int)((threads + 255) / 256), 256, 0, stream>>>(
                x, y, vals, rows, cols, nnz, flags);
            acc_add_out<<<(N_ELEM + 255) / 256, 256, 0, stream>>>(d_out, y, flags);
            float* t = x; x = y; y = t;
        }
    }

    finalize<<<(N_ELEM + 255) / 256, 256, 0, stream>>>(d_out, flags);
}

// Round 5
// 1216.362 us; speedup vs baseline: 10.1223x; 1.4411x over previous
//
#include <hip/hip_runtime.h>
#include <hip/hip_bf16.h>

#define N_USERS   100000
#define N_ITEMS   50000
#define N_NODES_C 150000
#define EMB       64
#define N_ELEM    (N_NODES_C * EMB)   // 9,600,000
#define SCAN_B    1024
#define SCAN_NB   ((N_NODES_C + SCAN_B - 1) / SCAN_B)   // 147

// ---- runtime dtype detection (fp32 vs bf16-packed) ----
__global__ void detect_dtypes(const unsigned int* __restrict__ emb_u32,
                              const unsigned int* __restrict__ vals_u32,
                              int* __restrict__ flags) {
    int t = threadIdx.x;
    int cnt_emb = 0, cnt_vals = 0;
    for (int k = t; k < 1024; k += 256) {
        unsigned e = (emb_u32[k] >> 7) & 0xFFu;
        cnt_emb += (e >= 100u && e <= 127u) ? 1 : 0;
        cnt_vals += (vals_u32[k] >> 15) & 1u;
    }
    __shared__ int s0[256], s1[256];
    s0[t] = cnt_emb; s1[t] = cnt_vals;
    __syncthreads();
    for (int s = 128; s > 0; s >>= 1) {
        if (t < s) { s0[t] += s0[t + s]; s1[t] += s1[t + s]; }
        __syncthreads();
    }
    if (t == 0) {
        flags[0] = (s0[0] > 512) ? 1 : 0;   // emb/out bf16?
        flags[1] = (s1[0] > 100) ? 0 : 1;   // vals bf16?
    }
}

__device__ __forceinline__ float load_f(const void* base, size_t i, int is_bf16) {
    if (is_bf16) return __bfloat162float(((const __hip_bfloat16*)base)[i]);
    return ((const float*)base)[i];
}
__device__ __forceinline__ void store_f(void* base, size_t i, int is_bf16, float v) {
    if (is_bf16) ((__hip_bfloat16*)base)[i] = __float2bfloat16(v);
    else ((float*)base)[i] = v;
}

// ---- init: h = ego (bf16); acc = ego (fp32, ws). d_out NOT touched. ----
__global__ void init_kernel(const void* __restrict__ eu,
                            const void* __restrict__ ei,
                            __hip_bfloat16* __restrict__ h,
                            float* __restrict__ acc,
                            const int* __restrict__ flags) {
    int i = blockIdx.x * blockDim.x + threadIdx.x;
    if (i >= N_ELEM) return;
    int ebf = flags[0];
    float f = (i < N_USERS * EMB) ? load_f(eu, i, ebf)
                                  : load_f(ei, i - N_USERS * EMB, ebf);
    h[i]   = __float2bfloat16(f);
    acc[i] = f;
}

// ---- zero the histogram counters (kernel, not hipMemsetAsync) ----
__global__ void zero_counts(int* __restrict__ counts) {
    int i = blockIdx.x * blockDim.x + threadIdx.x;
    if (i < N_NODES_C) counts[i] = 0;
}

// ---- CSR build A: histogram of rows (counts in row_off) ----
__global__ void hist_rows(const int* __restrict__ rows, int* __restrict__ counts, int nnz) {
    int i = blockIdx.x * blockDim.x + threadIdx.x;
    if (i < nnz) atomicAdd(&counts[rows[i]], 1);
}

// ---- B1: per-block exclusive scan of counts -> row_ptr (local), block sums ----
__global__ void scan_local(const int* __restrict__ counts,
                           int* __restrict__ scanned,
                           int* __restrict__ bsums) {
    __shared__ int lds[SCAN_B];
    int t = threadIdx.x;
    int gid = blockIdx.x * SCAN_B + t;
    int v = (gid < N_NODES_C) ? counts[gid] : 0;
    lds[t] = v;
    __syncthreads();
    for (int off = 1; off < SCAN_B; off <<= 1) {
        int u = (t >= off) ? lds[t - off] : 0;
        __syncthreads();
        lds[t] += u;
        __syncthreads();
    }
    if (gid < N_NODES_C) scanned[gid] = lds[t] - v;   // exclusive
    if (t == SCAN_B - 1) bsums[blockIdx.x] = lds[t];
}

// ---- B2: exclusive scan of the 147 block sums (single block) ----
__global__ void scan_partials(int* __restrict__ bsums, int* __restrict__ total) {
    __shared__ int lds[256];
    int t = threadIdx.x;
    int v = (t < SCAN_NB) ? bsums[t] : 0;
    lds[t] = v;
    __syncthreads();
    for (int off = 1; off < 256; off <<= 1) {
        int u = (t >= off) ? lds[t - off] : 0;
        __syncthreads();
        lds[t] += u;
        __syncthreads();
    }
    if (t < SCAN_NB) bsums[t] = lds[t] - v;
    if (t == 255) *total = lds[t];
}

// ---- B3: add block offsets; produce row_ptr and row_off ----
__global__ void scan_add(int* __restrict__ row_ptr, int* __restrict__ row_off,
                         const int* __restrict__ bsums, const int* __restrict__ total) {
    int gid = blockIdx.x * SCAN_B + threadIdx.x;
    if (gid < N_NODES_C) {
        int v = row_ptr[gid] + bsums[blockIdx.x];
        row_ptr[gid] = v;
        row_off[gid] = v;
    }
    if (gid == N_NODES_C - 1) row_ptr[N_NODES_C] = *total;
}

// ---- C: scatter edges into CSR order, packed (col, val_bits) ----
__global__ void scatter_edges(const int* __restrict__ rows, const int* __restrict__ cols,
                              const void* __restrict__ vals,
                              int* __restrict__ row_off,
                              int2* __restrict__ edges,
                              int nnz, const int* __restrict__ flags) {
    int i = blockIdx.x * blockDim.x + threadIdx.x;
    if (i >= nnz) return;
    int r = rows[i];
    int pos = atomicAdd(&row_off[r], 1);
    float v = load_f(vals, i, flags[1]);
    edges[pos] = make_int2(cols[i], __float_as_int(v));
}

// ---- CSR SpMM: one wave per row, lane = emb dim. bf16 x/y, fp32 acc in ws.
//      acc[i] += h_next; y written unless last layer. d_out never touched. ----
__global__ void spmm_csr(const __hip_bfloat16* __restrict__ x,
                         __hip_bfloat16* __restrict__ y,
                         float* __restrict__ accbuf,
                         const int2* __restrict__ edges,
                         const int* __restrict__ row_ptr,
                         int last) {
    int row = blockIdx.x * (blockDim.x >> 6) + (threadIdx.x >> 6);
    if (row >= N_NODES_C) return;
    int lane = threadIdx.x & 63;
    int beg = row_ptr[row], end = row_ptr[row + 1];
    float acc = 0.f;
    int e = beg;
    for (; e + 3 < end; e += 4) {
        int2 e0 = edges[e], e1 = edges[e + 1], e2 = edges[e + 2], e3 = edges[e + 3];
        float x0 = __bfloat162float(x[(size_t)e0.x * EMB + lane]);
        float x1 = __bfloat162float(x[(size_t)e1.x * EMB + lane]);
        float x2 = __bfloat162float(x[(size_t)e2.x * EMB + lane]);
        float x3 = __bfloat162float(x[(size_t)e3.x * EMB + lane]);
        acc += __int_as_float(e0.y) * x0;
        acc += __int_as_float(e1.y) * x1;
        acc += __int_as_float(e2.y) * x2;
        acc += __int_as_float(e3.y) * x3;
    }
    for (; e < end; ++e) {
        int2 ev = edges[e];
        acc += __int_as_float(ev.y) * __bfloat162float(x[(size_t)ev.x * EMB + lane]);
    }
    size_t i = (size_t)row * EMB + lane;
    if (!last) y[i] = __float2bfloat16(acc);
    accbuf[i] += acc;
}

// ---- finalize: the ONLY d_out write; pure function of acc ----
__global__ void finalize(const float* __restrict__ acc, void* __restrict__ out,
                         const int* __restrict__ flags) {
    int i = blockIdx.x * blockDim.x + threadIdx.x;
    if (i >= N_ELEM) return;
    store_f(out, i, flags[0], acc[i] * 0.25f);
}

extern "C" void kernel_launch(void* const* d_in, const int* in_sizes, int n_in,
                              void* d_out, int out_size, void* d_ws, size_t ws_size,
                              hipStream_t stream) {
    const void* eu   = d_in[0];
    const void* ei   = d_in[1];
    const void* vals = d_in[2];
    const int*  rows = (const int*)d_in[3];
    const int*  cols = (const int*)d_in[4];
    const int nnz = in_sizes[2];

    // ws layout (~116.4 MB, same footprint class as the R3 layout that fit)
    __hip_bfloat16* hA = (__hip_bfloat16*)d_ws;          // 9.6M bf16 (19.2 MB)
    __hip_bfloat16* hB = hA + N_ELEM;                    // 19.2 MB
    float* acc     = (float*)(hB + N_ELEM);              // 38.4 MB
    int2*  edges   = (int2*)(acc + N_ELEM);              // 38.4 MB
    int*   row_ptr = (int*)(edges + nnz);                // N_NODES_C + 2
    int*   row_off = row_ptr + (N_NODES_C + 2);          // N_NODES_C
    int*   bsums   = row_off + N_NODES_C;                // 256
    int*   total   = bsums + 256;                        // 1
    int*   flags   = total + 1;                          // 2

    detect_dtypes<<<1, 256, 0, stream>>>((const unsigned int*)eu,
                                         (const unsigned int*)vals, flags);

    init_kernel<<<(N_ELEM + 255) / 256, 256, 0, stream>>>(eu, ei, hA, acc, flags);

    // CSR build (kernels only — no memset nodes)
    zero_counts<<<(N_NODES_C + 255) / 256, 256, 0, stream>>>(row_off);
    hist_rows<<<(nnz + 255) / 256, 256, 0, stream>>>(rows, row_off, nnz);
    scan_local<<<SCAN_NB, SCAN_B, 0, stream>>>(row_off, row_ptr, bsums);
    scan_partials<<<1, 256, 0, stream>>>(bsums, total);
    scan_add<<<SCAN_NB, SCAN_B, 0, stream>>>(row_ptr, row_off, bsums, total);
    scatter_edges<<<(nnz + 255) / 256, 256, 0, stream>>>(rows, cols, vals, row_off,
                                                         edges, nnz, flags);

    // 3 propagation layers, accumulating into acc (fp32, ws)
    __hip_bfloat16* x = hA;
    __hip_bfloat16* y = hB;
    for (int layer = 0; layer < 3; ++layer) {
        int last = (layer == 2) ? 1 : 0;
        spmm_csr<<<(N_NODES_C + 3) / 4, 256, 0, stream>>>(x, y, acc, edges,
                                                          row_ptr, last);
        __hip_bfloat16* t = x; x = y; y = t;
    }

    // single d_out write
    finalize<<<(N_ELEM + 255) / 256, 256, 0, stream>>>(acc, d_out, flags);
}

// Round 6
// 885.584 us; speedup vs baseline: 13.9032x; 1.3735x over previous
//
#include <hip/hip_runtime.h>
#include <hip/hip_bf16.h>

#define N_USERS   100000
#define N_ITEMS   50000
#define N_NODES_C 150000
#define EMB       64
#define N_ELEM    (N_NODES_C * EMB)   // 9,600,000
#define SCAN_B    1024
#define SCAN_NB   ((N_NODES_C + SCAN_B - 1) / SCAN_B)   // 147
#define BKT_SHIFT 9
#define NBKT      ((N_NODES_C + 511) >> 9)              // 293
#define CH_EDGES  4096
#define EPT       16                                    // edges per thread, phase 1

// ---- runtime dtype detection (fp32 vs bf16-packed) ----
__global__ void detect_dtypes(const unsigned int* __restrict__ emb_u32,
                              const unsigned int* __restrict__ vals_u32,
                              int* __restrict__ flags) {
    int t = threadIdx.x;
    int cnt_emb = 0, cnt_vals = 0;
    for (int k = t; k < 1024; k += 256) {
        unsigned e = (emb_u32[k] >> 7) & 0xFFu;
        cnt_emb += (e >= 100u && e <= 127u) ? 1 : 0;
        cnt_vals += (vals_u32[k] >> 15) & 1u;
    }
    __shared__ int s0[256], s1[256];
    s0[t] = cnt_emb; s1[t] = cnt_vals;
    __syncthreads();
    for (int s = 128; s > 0; s >>= 1) {
        if (t < s) { s0[t] += s0[t + s]; s1[t] += s1[t + s]; }
        __syncthreads();
    }
    if (t == 0) {
        flags[0] = (s0[0] > 512) ? 1 : 0;   // emb/out bf16?
        flags[1] = (s1[0] > 100) ? 0 : 1;   // vals bf16?
    }
}

__device__ __forceinline__ float load_f(const void* base, size_t i, int is_bf16) {
    if (is_bf16) return __bfloat162float(((const __hip_bfloat16*)base)[i]);
    return ((const float*)base)[i];
}
__device__ __forceinline__ void store_f(void* base, size_t i, int is_bf16, float v) {
    if (is_bf16) ((__hip_bfloat16*)base)[i] = __float2bfloat16(v);
    else ((float*)base)[i] = v;
}
__device__ __forceinline__ unsigned int bf16_bits(float f) {
    __hip_bfloat16 h = __float2bfloat16(f);
    return (unsigned int)reinterpret_cast<unsigned short&>(h);
}

// ---- init: h0 = ego (bf16). d_out untouched. ----
__global__ void init_kernel(const void* __restrict__ eu,
                            const void* __restrict__ ei,
                            __hip_bfloat16* __restrict__ h0,
                            const int* __restrict__ flags) {
    int i = blockIdx.x * blockDim.x + threadIdx.x;
    if (i >= N_ELEM) return;
    int ebf = flags[0];
    float f = (i < N_USERS * EMB) ? load_f(eu, i, ebf)
                                  : load_f(ei, i - N_USERS * EMB, ebf);
    h0[i] = __float2bfloat16(f);
}

__global__ void zero_counts(int* __restrict__ counts) {
    int i = blockIdx.x * blockDim.x + threadIdx.x;
    if (i < N_NODES_C) counts[i] = 0;
}

__global__ void hist_rows(const int* __restrict__ rows, int* __restrict__ counts, int nnz) {
    int i = blockIdx.x * blockDim.x + threadIdx.x;
    if (i < nnz) atomicAdd(&counts[rows[i]], 1);
}

// ---- parallel exclusive scan over 150K counts -> row_ptr (+row_off copy) ----
__global__ void scan_local(const int* __restrict__ counts,
                           int* __restrict__ scanned,
                           int* __restrict__ bsums) {
    __shared__ int lds[SCAN_B];
    int t = threadIdx.x;
    int gid = blockIdx.x * SCAN_B + t;
    int v = (gid < N_NODES_C) ? counts[gid] : 0;
    lds[t] = v;
    __syncthreads();
    for (int off = 1; off < SCAN_B; off <<= 1) {
        int u = (t >= off) ? lds[t - off] : 0;
        __syncthreads();
        lds[t] += u;
        __syncthreads();
    }
    if (gid < N_NODES_C) scanned[gid] = lds[t] - v;
    if (t == SCAN_B - 1) bsums[blockIdx.x] = lds[t];
}
__global__ void scan_partials(int* __restrict__ bsums, int* __restrict__ total) {
    __shared__ int lds[256];
    int t = threadIdx.x;
    int v = (t < SCAN_NB) ? bsums[t] : 0;
    lds[t] = v;
    __syncthreads();
    for (int off = 1; off < 256; off <<= 1) {
        int u = (t >= off) ? lds[t - off] : 0;
        __syncthreads();
        lds[t] += u;
        __syncthreads();
    }
    if (t < SCAN_NB) bsums[t] = lds[t] - v;
    if (t == 255) *total = lds[t];
}
__global__ void scan_add(int* __restrict__ row_ptr, int* __restrict__ row_off,
                         const int* __restrict__ bsums, const int* __restrict__ total) {
    int gid = blockIdx.x * SCAN_B + threadIdx.x;
    if (gid < N_NODES_C) {
        int v = row_ptr[gid] + bsums[blockIdx.x];
        row_ptr[gid] = v;
        row_off[gid] = v;
    }
    if (gid == N_NODES_C - 1) row_ptr[N_NODES_C] = *total;
}

// ---- bucketed CSR build, phase 0: tails[b] = row_ptr[b<<9] ----
__global__ void init_tails(int* __restrict__ tails, const int* __restrict__ row_ptr) {
    int b = blockIdx.x * blockDim.x + threadIdx.x;
    if (b < NBKT) tails[b] = row_ptr[b << BKT_SHIFT];
}

// ---- phase 1: bin edges into NBKT coarse buckets (packed u64), bulk tail claims ----
__global__ void scatter_bucket(const int* __restrict__ rows, const int* __restrict__ cols,
                               const void* __restrict__ vals,
                               unsigned long long* __restrict__ tmp,
                               int* __restrict__ tails, int nnz,
                               const int* __restrict__ flags) {
    __shared__ int lcnt[NBKT];
    __shared__ int lbase[NBKT];
    int t = threadIdx.x;
    for (int b = t; b < NBKT; b += 256) lcnt[b] = 0;
    __syncthreads();
    int base = blockIdx.x * CH_EDGES;
    int vbf = flags[1];
    unsigned long long pk[EPT];
    unsigned int br[EPT];
    #pragma unroll
    for (int i = 0; i < EPT; ++i) {
        int e = base + i * 256 + t;
        if (e < nnz) {
            int r = rows[e];
            int c = cols[e];
            float v = load_f(vals, (size_t)e, vbf);
            int bk = r >> BKT_SHIFT;
            int rk = atomicAdd(&lcnt[bk], 1);
            pk[i] = ((unsigned long long)(unsigned)r << 34)
                  | ((unsigned long long)(unsigned)c << 16)
                  | (unsigned long long)bf16_bits(v);
            br[i] = ((unsigned)bk << 16) | (unsigned)rk;
        } else {
            br[i] = 0xFFFFFFFFu;
        }
    }
    __syncthreads();
    for (int b = t; b < NBKT; b += 256)
        lbase[b] = lcnt[b] ? atomicAdd(&tails[b], lcnt[b]) : 0;
    __syncthreads();
    #pragma unroll
    for (int i = 0; i < EPT; ++i) {
        if (br[i] != 0xFFFFFFFFu) {
            int bk = br[i] >> 16, rk = br[i] & 0xFFFFu;
            tmp[(size_t)lbase[bk] + rk] = pk[i];
        }
    }
}

// ---- phase 2: one block per bucket; scatter into CSR order (L2-local region) ----
__global__ void scatter_csr(const unsigned long long* __restrict__ tmp,
                            int2* __restrict__ edges,
                            const int* __restrict__ row_ptr) {
    __shared__ int cnt[512];
    int b = blockIdx.x, t = threadIdx.x;
    int rowbase = b << BKT_SHIFT;
    int nrows = N_NODES_C - rowbase; if (nrows > 512) nrows = 512;
    for (int j = t; j < nrows; j += 256) cnt[j] = row_ptr[rowbase + j];
    __syncthreads();
    int beg = row_ptr[rowbase];
    int end = row_ptr[rowbase + nrows];
    for (int e = beg + t; e < end; e += 256) {
        unsigned long long p = tmp[e];
        int r = (int)(p >> 34);
        int c = (int)((p >> 16) & 0x3FFFFu);
        unsigned int vb = (unsigned int)(p & 0xFFFFu) << 16;
        int pos = atomicAdd(&cnt[r - rowbase], 1);
        edges[pos] = make_int2(c, (int)vb);
    }
}

// ---- fallback direct scatter (used only if ws too small for tmp) ----
__global__ void scatter_edges(const int* __restrict__ rows, const int* __restrict__ cols,
                              const void* __restrict__ vals,
                              int* __restrict__ row_off,
                              int2* __restrict__ edges,
                              int nnz, const int* __restrict__ flags) {
    int i = blockIdx.x * blockDim.x + threadIdx.x;
    if (i >= nnz) return;
    int r = rows[i];
    int pos = atomicAdd(&row_off[r], 1);
    float v = load_f(vals, (size_t)i, flags[1]);
    edges[pos] = make_int2(cols[i], __float_as_int(v));
}

// ---- CSR SpMM: one wave per row, 4 edges in flight (quarter-wave each),
//      lane covers 4 bf16 elems via one uint2 load. y = A*x (bf16). ----
__global__ void spmm_csr4(const __hip_bfloat16* __restrict__ x,
                          __hip_bfloat16* __restrict__ y,
                          const int2* __restrict__ edges,
                          const int* __restrict__ row_ptr) {
    int row = blockIdx.x * 4 + (threadIdx.x >> 6);
    if (row >= N_NODES_C) return;
    int lane = threadIdx.x & 63;
    int q = lane >> 4;          // edge slot 0..3
    int s = lane & 15;          // elem group: covers elems [4s, 4s+3]
    int beg = row_ptr[row], end = row_ptr[row + 1];
    float a0 = 0.f, a1 = 0.f, a2 = 0.f, a3 = 0.f;
    for (int e = beg; e < end; e += 4) {
        int idx = e + q;
        bool ok = idx < end;
        int2 ed = ok ? edges[idx] : make_int2(0, 0);   // val=0 kills invalid lanes
        float v = __int_as_float(ed.y);
        const uint2 g = *reinterpret_cast<const uint2*>(
            x + ((size_t)(unsigned)ed.x << 6) + (s << 2));
        a0 += v * __uint_as_float((g.x & 0xFFFFu) << 16);
        a1 += v * __uint_as_float((g.x >> 16) << 16);
        a2 += v * __uint_as_float((g.y & 0xFFFFu) << 16);
        a3 += v * __uint_as_float((g.y >> 16) << 16);
    }
    // reduce the 4 edge-slots: elem partials live in lanes s, s+16, s+32, s+48
    for (int m = 16; m < 64; m <<= 1) {
        a0 += __shfl_xor(a0, m, 64);
        a1 += __shfl_xor(a1, m, 64);
        a2 += __shfl_xor(a2, m, 64);
        a3 += __shfl_xor(a3, m, 64);
    }
    if (q == 0) {
        uint2 o;
        o.x = bf16_bits(a0) | (bf16_bits(a1) << 16);
        o.y = bf16_bits(a2) | (bf16_bits(a3) << 16);
        *reinterpret_cast<uint2*>(y + ((size_t)row << 6) + (s << 2)) = o;
    }
}

// ---- finalize: the ONLY d_out write; out = (h0+h1+h2+h3)/4 ----
__global__ void finalize(const __hip_bfloat16* __restrict__ h0,
                         const __hip_bfloat16* __restrict__ h1,
                         const __hip_bfloat16* __restrict__ h2,
                         const __hip_bfloat16* __restrict__ h3,
                         void* __restrict__ out,
                         const int* __restrict__ flags) {
    int i = blockIdx.x * blockDim.x + threadIdx.x;
    if (i >= N_ELEM) return;
    float s = __bfloat162float(h0[i]) + __bfloat162float(h1[i])
            + __bfloat162float(h2[i]) + __bfloat162float(h3[i]);
    store_f(out, i, flags[0], s * 0.25f);
}

extern "C" void kernel_launch(void* const* d_in, const int* in_sizes, int n_in,
                              void* d_out, int out_size, void* d_ws, size_t ws_size,
                              hipStream_t stream) {
    const void* eu   = d_in[0];
    const void* ei   = d_in[1];
    const void* vals = d_in[2];
    const int*  rows = (const int*)d_in[3];
    const int*  cols = (const int*)d_in[4];
    const int nnz = in_sizes[2];

    // ws layout: h0..h3 | edges | int tables | (align8) tmp
    __hip_bfloat16* h[4];
    h[0] = (__hip_bfloat16*)d_ws;
    h[1] = h[0] + N_ELEM;
    h[2] = h[1] + N_ELEM;
    h[3] = h[2] + N_ELEM;                                 // 76.8 MB
    int2* edges  = (int2*)(h[3] + N_ELEM);                // 38.4 MB
    int* row_ptr = (int*)(edges + nnz);                   // N+2
    int* row_off = row_ptr + (N_NODES_C + 2);             // N
    int* bsums   = row_off + N_NODES_C;                   // 256
    int* total   = bsums + 256;                           // 1
    int* flags   = total + 1;                             // 2
    int* tails   = flags + 2;                             // NBKT
    char* pt = (char*)(tails + NBKT);
    unsigned long long* tmp =
        (unsigned long long*)(((uintptr_t)pt + 7) & ~(uintptr_t)7);  // nnz u64
    size_t need_full = (size_t)((char*)(tmp + nnz) - (char*)d_ws);
    bool bucketed = ws_size >= need_full;

    detect_dtypes<<<1, 256, 0, stream>>>((const unsigned int*)eu,
                                         (const unsigned int*)vals, flags);
    init_kernel<<<(N_ELEM + 255) / 256, 256, 0, stream>>>(eu, ei, h[0], flags);

    // row histogram + scan -> row_ptr
    zero_counts<<<(N_NODES_C + 255) / 256, 256, 0, stream>>>(row_off);
    hist_rows<<<(nnz + 255) / 256, 256, 0, stream>>>(rows, row_off, nnz);
    scan_local<<<SCAN_NB, SCAN_B, 0, stream>>>(row_off, row_ptr, bsums);
    scan_partials<<<1, 256, 0, stream>>>(bsums, total);
    scan_add<<<SCAN_NB, SCAN_B, 0, stream>>>(row_ptr, row_off, bsums, total);

    if (bucketed) {
        init_tails<<<(NBKT + 255) / 256, 256, 0, stream>>>(tails, row_ptr);
        scatter_bucket<<<(nnz + CH_EDGES - 1) / CH_EDGES, 256, 0, stream>>>(
            rows, cols, vals, tmp, tails, nnz, flags);
        scatter_csr<<<NBKT, 256, 0, stream>>>(tmp, edges, row_ptr);
    } else {
        scatter_edges<<<(nnz + 255) / 256, 256, 0, stream>>>(rows, cols, vals, row_off,
                                                             edges, nnz, flags);
    }

    // 3 propagation layers: h0 -> h1 -> h2 -> h3
    for (int layer = 0; layer < 3; ++layer) {
        spmm_csr4<<<(N_NODES_C + 3) / 4, 256, 0, stream>>>(h[layer], h[layer + 1],
                                                           edges, row_ptr);
    }

    finalize<<<(N_ELEM + 255) / 256, 256, 0, stream>>>(h[0], h[1], h[2], h[3],
                                                       d_out, flags);
}

// Round 7
// 738.692 us; speedup vs baseline: 16.6679x; 1.1989x over previous
//
#include <hip/hip_runtime.h>
#include <hip/hip_bf16.h>

#define N_USERS   100000
#define N_ITEMS   50000
#define N_NODES_C 150000
#define EMB       64
#define N_ELEM    (N_NODES_C * EMB)   // 9,600,000
#define BKT_SHIFT 9
#define NBKT      ((N_NODES_C + 511) >> 9)              // 293
#define CH_EDGES  4096
#define EPT       16                                    // edges/thread, scatter_bucket

// ---- runtime dtype detection (fp32 vs bf16-packed) ----
__global__ void detect_dtypes(const unsigned int* __restrict__ emb_u32,
                              const unsigned int* __restrict__ vals_u32,
                              int* __restrict__ flags) {
    int t = threadIdx.x;
    int cnt_emb = 0, cnt_vals = 0;
    for (int k = t; k < 1024; k += 256) {
        unsigned e = (emb_u32[k] >> 7) & 0xFFu;
        cnt_emb += (e >= 100u && e <= 127u) ? 1 : 0;
        cnt_vals += (vals_u32[k] >> 15) & 1u;
    }
    __shared__ int s0[256], s1[256];
    s0[t] = cnt_emb; s1[t] = cnt_vals;
    __syncthreads();
    for (int s = 128; s > 0; s >>= 1) {
        if (t < s) { s0[t] += s0[t + s]; s1[t] += s1[t + s]; }
        __syncthreads();
    }
    if (t == 0) {
        flags[0] = (s0[0] > 512) ? 1 : 0;   // emb/out bf16?
        flags[1] = (s1[0] > 100) ? 0 : 1;   // vals bf16?
    }
}

__device__ __forceinline__ float load_f(const void* base, size_t i, int is_bf16) {
    if (is_bf16) return __bfloat162float(((const __hip_bfloat16*)base)[i]);
    return ((const float*)base)[i];
}
__device__ __forceinline__ void store_f(void* base, size_t i, int is_bf16, float v) {
    if (is_bf16) ((__hip_bfloat16*)base)[i] = __float2bfloat16(v);
    else ((float*)base)[i] = v;
}
__device__ __forceinline__ unsigned int bf16_bits(float f) {
    __hip_bfloat16 h = __float2bfloat16(f);
    return (unsigned int)reinterpret_cast<unsigned short&>(h);
}

// ---- init: h0 = ego (bf16). d_out untouched until finalize. ----
__global__ void init_kernel(const void* __restrict__ eu,
                            const void* __restrict__ ei,
                            __hip_bfloat16* __restrict__ h0,
                            const int* __restrict__ flags) {
    int i = blockIdx.x * blockDim.x + threadIdx.x;
    if (i >= N_ELEM) return;
    int ebf = flags[0];
    float f = (i < N_USERS * EMB) ? load_f(eu, i, ebf)
                                  : load_f(ei, i - N_USERS * EMB, ebf);
    h0[i] = __float2bfloat16(f);
}

// ---- zero the bucket counters ----
__global__ void zero_bkt(int* __restrict__ bktcnt) {
    int i = blockIdx.x * blockDim.x + threadIdx.x;
    if (i < NBKT) bktcnt[i] = 0;
}

// ---- LDS-privatized histogram over 293 coarse buckets ----
__global__ void bucket_hist(const int* __restrict__ rows, int* __restrict__ bktcnt,
                            int nnz) {
    __shared__ int l[NBKT];
    int t = threadIdx.x;
    for (int b = t; b < NBKT; b += 256) l[b] = 0;
    __syncthreads();
    int base = blockIdx.x * CH_EDGES;
    int lim = base + CH_EDGES; if (lim > nnz) lim = nnz;
    for (int i = base + t; i < lim; i += 256)
        atomicAdd(&l[rows[i] >> BKT_SHIFT], 1);
    __syncthreads();
    for (int b = t; b < NBKT; b += 256)
        if (l[b]) atomicAdd(&bktcnt[b], l[b]);
}

// ---- exclusive scan of 293 bucket counts -> bktbase[0..NBKT], tails copy ----
__global__ void scan_bkt(const int* __restrict__ bktcnt,
                         int* __restrict__ bktbase, int* __restrict__ tails) {
    __shared__ int l[512];
    int t = threadIdx.x;
    int v = (t < NBKT) ? bktcnt[t] : 0;
    l[t] = v;
    __syncthreads();
    for (int off = 1; off < 512; off <<= 1) {
        int u = (t >= off) ? l[t - off] : 0;
        __syncthreads();
        l[t] += u;
        __syncthreads();
    }
    int excl = l[t] - v;
    if (t < NBKT) { bktbase[t] = excl; tails[t] = excl; }
    if (t == NBKT - 1) bktbase[NBKT] = l[t];
}

// ---- bin edges into buckets (packed u64), bulk tail claims ----
__global__ void scatter_bucket(const int* __restrict__ rows, const int* __restrict__ cols,
                               const void* __restrict__ vals,
                               unsigned long long* __restrict__ tmp,
                               int* __restrict__ tails, int nnz,
                               const int* __restrict__ flags) {
    __shared__ int lcnt[NBKT];
    __shared__ int lbase[NBKT];
    int t = threadIdx.x;
    for (int b = t; b < NBKT; b += 256) lcnt[b] = 0;
    __syncthreads();
    int base = blockIdx.x * CH_EDGES;
    int vbf = flags[1];
    unsigned long long pk[EPT];
    unsigned int br[EPT];
    #pragma unroll
    for (int i = 0; i < EPT; ++i) {
        int e = base + i * 256 + t;
        if (e < nnz) {
            int r = rows[e];
            int c = cols[e];
            float v = load_f(vals, (size_t)e, vbf);
            int bk = r >> BKT_SHIFT;
            int rk = atomicAdd(&lcnt[bk], 1);
            pk[i] = ((unsigned long long)(unsigned)r << 34)
                  | ((unsigned long long)(unsigned)c << 16)
                  | (unsigned long long)bf16_bits(v);
            br[i] = ((unsigned)bk << 16) | (unsigned)rk;
        } else {
            br[i] = 0xFFFFFFFFu;
        }
    }
    __syncthreads();
    for (int b = t; b < NBKT; b += 256)
        lbase[b] = lcnt[b] ? atomicAdd(&tails[b], lcnt[b]) : 0;
    __syncthreads();
    #pragma unroll
    for (int i = 0; i < EPT; ++i) {
        if (br[i] != 0xFFFFFFFFu) {
            int bk = br[i] >> 16, rk = br[i] & 0xFFFFu;
            tmp[(size_t)lbase[bk] + rk] = pk[i];
        }
    }
}

// ---- one block per bucket: count rows, LDS scan -> row_ptr slice,
//      then scatter edges into exact CSR order (L2-local segment). ----
__global__ void bucket_csr(const unsigned long long* __restrict__ tmp,
                           int2* __restrict__ edges,
                           const int* __restrict__ bktbase,
                           int* __restrict__ row_ptr) {
    __shared__ int cnt[512];
    __shared__ int off[512];
    int b = blockIdx.x, t = threadIdx.x;
    int rowbase = b << BKT_SHIFT;
    int nrows = N_NODES_C - rowbase; if (nrows > 512) nrows = 512;
    cnt[t] = 0;
    __syncthreads();
    int beg = bktbase[b], end = bktbase[b + 1];
    for (int e = beg + t; e < end; e += 512) {
        int rloc = (int)(tmp[e] >> 34) - rowbase;
        atomicAdd(&cnt[rloc], 1);
    }
    __syncthreads();
    int v = cnt[t];
    off[t] = v;
    __syncthreads();
    for (int o = 1; o < 512; o <<= 1) {
        int u = (t >= o) ? off[t - o] : 0;
        __syncthreads();
        off[t] += u;
        __syncthreads();
    }
    int excl = off[t] - v;
    __syncthreads();
    off[t] = beg + excl;                       // global write cursor per row
    if (t < nrows) row_ptr[rowbase + t] = beg + excl;
    if (b == NBKT - 1 && t == 0) row_ptr[N_NODES_C] = end;
    __syncthreads();
    for (int e = beg + t; e < end; e += 512) {
        unsigned long long p = tmp[e];
        int rloc = (int)(p >> 34) - rowbase;
        int c = (int)((p >> 16) & 0x3FFFFu);
        int pos = atomicAdd(&off[rloc], 1);
        edges[pos] = make_int2(c, (int)((unsigned)(p & 0xFFFFu) << 16));
    }
}

// ---- CSR SpMM: one wave per row, 4 edges in flight (quarter-wave each),
//      lane covers 4 bf16 elems via one uint2 load. y = A*x (bf16). ----
__global__ void spmm_csr4(const __hip_bfloat16* __restrict__ x,
                          __hip_bfloat16* __restrict__ y,
                          const int2* __restrict__ edges,
                          const int* __restrict__ row_ptr) {
    int row = blockIdx.x * 4 + (threadIdx.x >> 6);
    if (row >= N_NODES_C) return;
    int lane = threadIdx.x & 63;
    int q = lane >> 4;          // edge slot 0..3
    int s = lane & 15;          // elem group: covers elems [4s, 4s+3]
    int beg = row_ptr[row], end = row_ptr[row + 1];
    float a0 = 0.f, a1 = 0.f, a2 = 0.f, a3 = 0.f;
    for (int e = beg; e < end; e += 4) {
        int idx = e + q;
        bool ok = idx < end;
        int2 ed = ok ? edges[idx] : make_int2(0, 0);   // val=0 kills invalid lanes
        float v = __int_as_float(ed.y);
        const uint2 g = *reinterpret_cast<const uint2*>(
            x + ((size_t)(unsigned)ed.x << 6) + (s << 2));
        a0 += v * __uint_as_float((g.x & 0xFFFFu) << 16);
        a1 += v * __uint_as_float((g.x >> 16) << 16);
        a2 += v * __uint_as_float((g.y & 0xFFFFu) << 16);
        a3 += v * __uint_as_float((g.y >> 16) << 16);
    }
    for (int m = 16; m < 64; m <<= 1) {
        a0 += __shfl_xor(a0, m, 64);
        a1 += __shfl_xor(a1, m, 64);
        a2 += __shfl_xor(a2, m, 64);
        a3 += __shfl_xor(a3, m, 64);
    }
    if (q == 0) {
        uint2 o;
        o.x = bf16_bits(a0) | (bf16_bits(a1) << 16);
        o.y = bf16_bits(a2) | (bf16_bits(a3) << 16);
        *reinterpret_cast<uint2*>(y + ((size_t)row << 6) + (s << 2)) = o;
    }
}

// ---- finalize: the ONLY d_out write; out = (h0+h1+h2+h3)/4 ----
__global__ void finalize(const __hip_bfloat16* __restrict__ h0,
                         const __hip_bfloat16* __restrict__ h1,
                         const __hip_bfloat16* __restrict__ h2,
                         const __hip_bfloat16* __restrict__ h3,
                         void* __restrict__ out,
                         const int* __restrict__ flags) {
    int i = blockIdx.x * blockDim.x + threadIdx.x;
    if (i >= N_ELEM) return;
    float s = __bfloat162float(h0[i]) + __bfloat162float(h1[i])
            + __bfloat162float(h2[i]) + __bfloat162float(h3[i]);
    store_f(out, i, flags[0], s * 0.25f);
}

extern "C" void kernel_launch(void* const* d_in, const int* in_sizes, int n_in,
                              void* d_out, int out_size, void* d_ws, size_t ws_size,
                              hipStream_t stream) {
    const void* eu   = d_in[0];
    const void* ei   = d_in[1];
    const void* vals = d_in[2];
    const int*  rows = (const int*)d_in[3];
    const int*  cols = (const int*)d_in[4];
    const int nnz = in_sizes[2];

    // ws layout: h0..h3 | edges | tables | (align8) tmp  (~154.3 MB, fits: R6)
    __hip_bfloat16* h[4];
    h[0] = (__hip_bfloat16*)d_ws;
    h[1] = h[0] + N_ELEM;
    h[2] = h[1] + N_ELEM;
    h[3] = h[2] + N_ELEM;                                 // 76.8 MB
    int2* edges   = (int2*)(h[3] + N_ELEM);               // 38.4 MB
    int* row_ptr  = (int*)(edges + nnz);                  // N_NODES_C + 1
    int* bktcnt   = row_ptr + (N_NODES_C + 1);            // NBKT
    int* bktbase  = bktcnt + NBKT;                        // NBKT + 1
    int* tails    = bktbase + (NBKT + 1);                 // NBKT
    int* flags    = tails + NBKT;                         // 2
    char* pt = (char*)(flags + 2);
    unsigned long long* tmp =
        (unsigned long long*)(((uintptr_t)pt + 7) & ~(uintptr_t)7);  // nnz u64

    detect_dtypes<<<1, 256, 0, stream>>>((const unsigned int*)eu,
                                         (const unsigned int*)vals, flags);
    init_kernel<<<(N_ELEM + 255) / 256, 256, 0, stream>>>(eu, ei, h[0], flags);

    // bucket-first CSR build (no global per-row histogram)
    int nchunks = (nnz + CH_EDGES - 1) / CH_EDGES;
    zero_bkt<<<(NBKT + 255) / 256, 256, 0, stream>>>(bktcnt);
    bucket_hist<<<nchunks, 256, 0, stream>>>(rows, bktcnt, nnz);
    scan_bkt<<<1, 512, 0, stream>>>(bktcnt, bktbase, tails);
    scatter_bucket<<<nchunks, 256, 0, stream>>>(rows, cols, vals, tmp, tails, nnz, flags);
    bucket_csr<<<NBKT, 512, 0, stream>>>(tmp, edges, bktbase, row_ptr);

    // 3 propagation layers: h0 -> h1 -> h2 -> h3
    for (int layer = 0; layer < 3; ++layer) {
        spmm_csr4<<<(N_NODES_C + 3) / 4, 256, 0, stream>>>(h[layer], h[layer + 1],
                                                           edges, row_ptr);
    }

    finalize<<<(N_ELEM + 255) / 256, 256, 0, stream>>>(h[0], h[1], h[2], h[3],
                                                       d_out, flags);
}

// Round 8
// 534.552 us; speedup vs baseline: 23.0332x; 1.3819x over previous
//
#include <hip/hip_runtime.h>
#include <hip/hip_bf16.h>

#define N_USERS   100000
#define N_ITEMS   50000
#define N_NODES_C 150000
#define EMB       64
#define N_ELEM    (N_NODES_C * EMB)   // 9,600,000
#define BKT_SHIFT 9
#define NBKT      ((N_NODES_C + 511) >> 9)              // 293
#define BKT_CAP   20480                                 // mean 16384 + 32 sigma
#define CH_EDGES  4096
#define EPT       16                                    // edges/thread, scatter_bucket

// ---- dtype detection (fp32 vs bf16-packed) + zero bucket tails ----
__global__ void detect_and_zero(const unsigned int* __restrict__ emb_u32,
                                const unsigned int* __restrict__ vals_u32,
                                int* __restrict__ flags,
                                int* __restrict__ tails) {
    int t = threadIdx.x;
    for (int b = t; b < NBKT; b += 256) tails[b] = 0;
    int cnt_emb = 0, cnt_vals = 0;
    for (int k = t; k < 1024; k += 256) {
        unsigned e = (emb_u32[k] >> 7) & 0xFFu;
        cnt_emb += (e >= 100u && e <= 127u) ? 1 : 0;
        cnt_vals += (vals_u32[k] >> 15) & 1u;
    }
    __shared__ int s0[256], s1[256];
    s0[t] = cnt_emb; s1[t] = cnt_vals;
    __syncthreads();
    for (int s = 128; s > 0; s >>= 1) {
        if (t < s) { s0[t] += s0[t + s]; s1[t] += s1[t + s]; }
        __syncthreads();
    }
    if (t == 0) {
        flags[0] = (s0[0] > 512) ? 1 : 0;   // emb/out bf16?
        flags[1] = (s1[0] > 100) ? 0 : 1;   // vals bf16?
    }
}

__device__ __forceinline__ float load_f(const void* base, size_t i, int is_bf16) {
    if (is_bf16) return __bfloat162float(((const __hip_bfloat16*)base)[i]);
    return ((const float*)base)[i];
}
__device__ __forceinline__ unsigned int bf16_bits(float f) {
    __hip_bfloat16 h = __float2bfloat16(f);
    return (unsigned int)reinterpret_cast<unsigned short&>(h);
}
__device__ __forceinline__ float lo_bf(unsigned int u) {
    return __uint_as_float((u & 0xFFFFu) << 16);
}
__device__ __forceinline__ float hi_bf(unsigned int u) {
    return __uint_as_float((u >> 16) << 16);
}

// ---- init: h0 = ego (bf16). d_out untouched until the last spmm. ----
__global__ void init_kernel(const void* __restrict__ eu,
                            const void* __restrict__ ei,
                            __hip_bfloat16* __restrict__ h0,
                            const int* __restrict__ flags) {
    int i = blockIdx.x * blockDim.x + threadIdx.x;
    if (i >= N_ELEM) return;
    int ebf = flags[0];
    float f = (i < N_USERS * EMB) ? load_f(eu, i, ebf)
                                  : load_f(ei, i - N_USERS * EMB, ebf);
    h0[i] = __float2bfloat16(f);
}

// ---- bin edges into fixed-capacity buckets (packed u64), bulk tail claims ----
__global__ void scatter_bucket(const int* __restrict__ rows, const int* __restrict__ cols,
                               const void* __restrict__ vals,
                               unsigned long long* __restrict__ tmp,
                               int* __restrict__ tails, int nnz,
                               const int* __restrict__ flags) {
    __shared__ int lcnt[NBKT];
    __shared__ int lbase[NBKT];
    int t = threadIdx.x;
    for (int b = t; b < NBKT; b += 256) lcnt[b] = 0;
    __syncthreads();
    int base = blockIdx.x * CH_EDGES;
    int vbf = flags[1];
    unsigned long long pk[EPT];
    unsigned int br[EPT];
    #pragma unroll
    for (int i = 0; i < EPT; ++i) {
        int e = base + i * 256 + t;
        if (e < nnz) {
            int r = rows[e];
            int c = cols[e];
            float v = load_f(vals, (size_t)e, vbf);
            int bk = r >> BKT_SHIFT;
            int rk = atomicAdd(&lcnt[bk], 1);
            pk[i] = ((unsigned long long)(unsigned)r << 34)
                  | ((unsigned long long)(unsigned)c << 16)
                  | (unsigned long long)bf16_bits(v);
            br[i] = ((unsigned)bk << 16) | (unsigned)rk;
        } else {
            br[i] = 0xFFFFFFFFu;
        }
    }
    __syncthreads();
    for (int b = t; b < NBKT; b += 256)
        lbase[b] = lcnt[b] ? atomicAdd(&tails[b], lcnt[b]) : 0;
    __syncthreads();
    #pragma unroll
    for (int i = 0; i < EPT; ++i) {
        if (br[i] != 0xFFFFFFFFu) {
            int bk = br[i] >> 16, rk = br[i] & 0xFFFFu;
            int pos = lbase[bk] + rk;
            if (pos < BKT_CAP)
                tmp[(size_t)bk * BKT_CAP + pos] = pk[i];
        }
    }
}

// ---- exclusive scan of 293 bucket counts -> bktbase[0..NBKT] ----
__global__ void scan_bkt(const int* __restrict__ tails, int* __restrict__ bktbase) {
    __shared__ int l[512];
    int t = threadIdx.x;
    int v = (t < NBKT) ? tails[t] : 0;
    l[t] = v;
    __syncthreads();
    for (int off = 1; off < 512; off <<= 1) {
        int u = (t >= off) ? l[t - off] : 0;
        __syncthreads();
        l[t] += u;
        __syncthreads();
    }
    if (t < NBKT) bktbase[t] = l[t] - v;
    if (t == NBKT - 1) bktbase[NBKT] = l[t];
}

// ---- one block per bucket: count rows, LDS scan -> row_ptr slice,
//      scatter slot-region edges into exact CSR order (L2-local). ----
__global__ void bucket_csr(const unsigned long long* __restrict__ tmp,
                           int2* __restrict__ edges,
                           const int* __restrict__ tails,
                           const int* __restrict__ bktbase,
                           int* __restrict__ row_ptr) {
    __shared__ int cnt[512];
    __shared__ int off[512];
    int b = blockIdx.x, t = threadIdx.x;
    int rowbase = b << BKT_SHIFT;
    int nrows = N_NODES_C - rowbase; if (nrows > 512) nrows = 512;
    int n = tails[b];
    if (n > BKT_CAP) n = BKT_CAP;
    const unsigned long long* src = tmp + (size_t)b * BKT_CAP;
    int obase = bktbase[b];
    cnt[t] = 0;
    __syncthreads();
    for (int e = t; e < n; e += 512)
        atomicAdd(&cnt[(int)(src[e] >> 34) - rowbase], 1);
    __syncthreads();
    int v = cnt[t];
    off[t] = v;
    __syncthreads();
    for (int o = 1; o < 512; o <<= 1) {
        int u = (t >= o) ? off[t - o] : 0;
        __syncthreads();
        off[t] += u;
        __syncthreads();
    }
    int excl = off[t] - v;
    __syncthreads();
    off[t] = obase + excl;
    if (t < nrows) row_ptr[rowbase + t] = obase + excl;
    if (b == NBKT - 1 && t == 0) row_ptr[N_NODES_C] = obase + n;
    __syncthreads();
    for (int e = t; e < n; e += 512) {
        unsigned long long p = src[e];
        int rloc = (int)(p >> 34) - rowbase;
        int c = (int)((p >> 16) & 0x3FFFFu);
        int pos = atomicAdd(&off[rloc], 1);
        edges[pos] = make_int2(c, (int)((unsigned)(p & 0xFFFFu) << 16));
    }
}

#define ACC8(v, g)                      \
    a0 += (v) * lo_bf((g).x);           \
    a1 += (v) * hi_bf((g).x);           \
    a2 += (v) * lo_bf((g).y);           \
    a3 += (v) * hi_bf((g).y);           \
    a4 += (v) * lo_bf((g).z);           \
    a5 += (v) * hi_bf((g).z);           \
    a6 += (v) * lo_bf((g).w);           \
    a7 += (v) * hi_bf((g).w);

// ---- CSR SpMM: one wave/row, 8 edge-slots (8 lanes x uint4 = full 128B row),
//      2x unroll -> 16 edges in flight. Butterfly reduce over slots.
//      last==0: y = A*x (bf16).  last==1: d_out = (h0+h1+h2+A*x)/4 (sole write).
__global__ void spmm8(const __hip_bfloat16* __restrict__ x,
                      __hip_bfloat16* __restrict__ y,
                      const int2* __restrict__ edges,
                      const int* __restrict__ row_ptr,
                      const __hip_bfloat16* __restrict__ h0,
                      const __hip_bfloat16* __restrict__ h1,
                      void* __restrict__ out,
                      const int* __restrict__ flags,
                      int last) {
    int row = blockIdx.x * 4 + (threadIdx.x >> 6);
    if (row >= N_NODES_C) return;
    int lane = threadIdx.x & 63;
    int slot = lane >> 3;       // edge slot 0..7
    int s    = lane & 7;        // elem octet: elems [8s, 8s+7]
    int beg = row_ptr[row], end = row_ptr[row + 1];
    float a0 = 0.f, a1 = 0.f, a2 = 0.f, a3 = 0.f,
          a4 = 0.f, a5 = 0.f, a6 = 0.f, a7 = 0.f;
    for (int e = beg; e < end; e += 16) {
        int iA = e + slot;
        int iB = e + 8 + slot;
        int2 edA = (iA < end) ? edges[iA] : make_int2(0, 0);
        int2 edB = (iB < end) ? edges[iB] : make_int2(0, 0);
        float vA = __int_as_float(edA.y);
        float vB = __int_as_float(edB.y);
        const uint4 gA = *reinterpret_cast<const uint4*>(
            x + ((size_t)(unsigned)edA.x << 6) + (s << 3));
        const uint4 gB = *reinterpret_cast<const uint4*>(
            x + ((size_t)(unsigned)edB.x << 6) + (s << 3));
        ACC8(vA, gA);
        ACC8(vB, gB);
    }
    #pragma unroll
    for (int m = 8; m < 64; m <<= 1) {
        a0 += __shfl_xor(a0, m, 64);
        a1 += __shfl_xor(a1, m, 64);
        a2 += __shfl_xor(a2, m, 64);
        a3 += __shfl_xor(a3, m, 64);
        a4 += __shfl_xor(a4, m, 64);
        a5 += __shfl_xor(a5, m, 64);
        a6 += __shfl_xor(a6, m, 64);
        a7 += __shfl_xor(a7, m, 64);
    }
    if (slot != 0) return;
    size_t base = ((size_t)row << 6) + (s << 3);
    if (!last) {
        uint4 o;
        o.x = bf16_bits(a0) | (bf16_bits(a1) << 16);
        o.y = bf16_bits(a2) | (bf16_bits(a3) << 16);
        o.z = bf16_bits(a4) | (bf16_bits(a5) << 16);
        o.w = bf16_bits(a6) | (bf16_bits(a7) << 16);
        *reinterpret_cast<uint4*>(y + base) = o;
    } else {
        const uint4 r0 = *reinterpret_cast<const uint4*>(h0 + base);
        const uint4 r1 = *reinterpret_cast<const uint4*>(h1 + base);
        const uint4 r2 = *reinterpret_cast<const uint4*>(x + base);  // x == h2
        float f0 = (lo_bf(r0.x) + lo_bf(r1.x) + lo_bf(r2.x) + a0) * 0.25f;
        float f1 = (hi_bf(r0.x) + hi_bf(r1.x) + hi_bf(r2.x) + a1) * 0.25f;
        float f2 = (lo_bf(r0.y) + lo_bf(r1.y) + lo_bf(r2.y) + a2) * 0.25f;
        float f3 = (hi_bf(r0.y) + hi_bf(r1.y) + hi_bf(r2.y) + a3) * 0.25f;
        float f4 = (lo_bf(r0.z) + lo_bf(r1.z) + lo_bf(r2.z) + a4) * 0.25f;
        float f5 = (hi_bf(r0.z) + hi_bf(r1.z) + hi_bf(r2.z) + a5) * 0.25f;
        float f6 = (lo_bf(r0.w) + lo_bf(r1.w) + lo_bf(r2.w) + a6) * 0.25f;
        float f7 = (hi_bf(r0.w) + hi_bf(r1.w) + hi_bf(r2.w) + a7) * 0.25f;
        if (flags[0]) {
            uint4 o;
            o.x = bf16_bits(f0) | (bf16_bits(f1) << 16);
            o.y = bf16_bits(f2) | (bf16_bits(f3) << 16);
            o.z = bf16_bits(f4) | (bf16_bits(f5) << 16);
            o.w = bf16_bits(f6) | (bf16_bits(f7) << 16);
            *reinterpret_cast<uint4*>((__hip_bfloat16*)out + base) = o;
        } else {
            float* op = (float*)out + base;
            float4 q0 = make_float4(f0, f1, f2, f3);
            float4 q1 = make_float4(f4, f5, f6, f7);
            *reinterpret_cast<float4*>(op)     = q0;
            *reinterpret_cast<float4*>(op + 4) = q1;
        }
    }
}

extern "C" void kernel_launch(void* const* d_in, const int* in_sizes, int n_in,
                              void* d_out, int out_size, void* d_ws, size_t ws_size,
                              hipStream_t stream) {
    const void* eu   = d_in[0];
    const void* ei   = d_in[1];
    const void* vals = d_in[2];
    const int*  rows = (const int*)d_in[3];
    const int*  cols = (const int*)d_in[4];
    const int nnz = in_sizes[2];

    // ws layout: h0..h2 (57.6MB) | edges (38.4MB) | tables | align8 tmp (48MB)
    __hip_bfloat16* h[3];
    h[0] = (__hip_bfloat16*)d_ws;
    h[1] = h[0] + N_ELEM;
    h[2] = h[1] + N_ELEM;
    int2* edges   = (int2*)(h[2] + N_ELEM);
    int* row_ptr  = (int*)(edges + nnz);                  // N_NODES_C + 1
    int* bktbase  = row_ptr + (N_NODES_C + 1);            // NBKT + 1
    int* tails    = bktbase + (NBKT + 1);                 // NBKT
    int* flags    = tails + NBKT;                         // 2
    char* pt = (char*)(flags + 2);
    unsigned long long* tmp =
        (unsigned long long*)(((uintptr_t)pt + 7) & ~(uintptr_t)7);  // NBKT*CAP u64

    detect_and_zero<<<1, 256, 0, stream>>>((const unsigned int*)eu,
                                           (const unsigned int*)vals, flags, tails);
    init_kernel<<<(N_ELEM + 255) / 256, 256, 0, stream>>>(eu, ei, h[0], flags);

    // CSR build: slot-bucket scatter -> bucket scan -> per-bucket CSR sort
    int nchunks = (nnz + CH_EDGES - 1) / CH_EDGES;
    scatter_bucket<<<nchunks, 256, 0, stream>>>(rows, cols, vals, tmp, tails, nnz, flags);
    scan_bkt<<<1, 512, 0, stream>>>(tails, bktbase);
    bucket_csr<<<NBKT, 512, 0, stream>>>(tmp, edges, tails, bktbase, row_ptr);

    // layers: h0 -> h1 -> h2 -> (fused final) d_out
    int nsb = (N_NODES_C + 3) / 4;
    spmm8<<<nsb, 256, 0, stream>>>(h[0], h[1], edges, row_ptr,
                                   nullptr, nullptr, nullptr, flags, 0);
    spmm8<<<nsb, 256, 0, stream>>>(h[1], h[2], edges, row_ptr,
                                   nullptr, nullptr, nullptr, flags, 0);
    spmm8<<<nsb, 256, 0, stream>>>(h[2], nullptr, edges, row_ptr,
                                   h[0], h[1], d_out, flags, 1);
}